// Round 3
// baseline (732.410 us; speedup 1.0000x reference)
//
#include <hip/hip_runtime.h>
#include <stdint.h>

// HashGrid forward, R5: explicit load batching for MLP + dense corner-pairing.
// R4b counters: hash8 = 312 us, 1.05 TB/s, VALUBusy 5.8%, Occ 81%, VGPR=28.
// VGPR=28 is the smoking gun: the compiler serialized the 16 gathers (can't
// hold 16 dwordx2 results in 28 regs) -> ~183 cyc per wave-gather = raw L2
// latency, MLP-starved. TCP line-serialization floor is ~110 us; BW floor
// ~25 us. Fix: compute ALL corner addresses, issue ALL loads into register
// arrays, THEN accumulate (program order forces back-to-back issue).
// Dense levels (idx = cx + cy*res, no wrap since res*(res+1) < T): the two
// x-corners are ADJACENT entries -> one 16B load per dy-pair (half the
// gather instrs + half the L2 line requests for levels 0-9).
// Merge reverted to the R3-measured skeleton (single-phase 36 KB LDS, plain
// loads/stores, 201 us) + the same batching/pairing (32 gathers -> 16 paired
// loads, all in flight).
//
// Correctness-critical (unchanged, passed at 4.8e-7): pos = x*scale + 0.5 as
// separate __fmul_rn/__fadd_rn (no FMA -> floor() cell matches numpy);
// weights wx*wy as one multiply each; fmaf accumulation order
// (0,0),(0,1),(1,0),(1,1) starting from 0.0f; ws round-trips bits via u64.

constexpr int      kNPoints = 2097152;
constexpr uint32_t kT       = 524288u;      // 2^19
constexpr uint32_t kTMask   = kT - 1u;
constexpr uint32_t kPrimeY  = 2654435761u;  // tcnn 2D spatial-hash prime

__device__ __forceinline__ float2 nt_load_f2(const float2* p) {
    union { unsigned long long u; float2 f2; } u;
    u.u = __builtin_nontemporal_load(reinterpret_cast<const unsigned long long*>(p));
    return u.f2;
}

__device__ __forceinline__ void nt_store_f2(float2* p, float2 v) {
    union { unsigned long long u; float2 f2; } u; u.f2 = v;
    __builtin_nontemporal_store(u.u, reinterpret_cast<unsigned long long*>(p));
}

// 16B load spanning two ADJACENT table entries (8B-aligned; gfx9+ allows
// dword-aligned dwordx4 / the LSV merges into one b128). lo = entry p[0]
// (corner dx=0), hi = entry p[1] (corner dx=1).
struct PairLd { float2 lo, hi; };
__device__ __forceinline__ PairLd load_pair(const float2* __restrict__ p) {
    PairLd r;
    __builtin_memcpy(&r, p, 16);
    return r;
}

// scale = 16*1.5^l - 1, exactly fp32-representable for all 16 levels.
__device__ __host__ inline void level_consts(int l, float& sc, uint32_t& re, int& dense) {
    const float ksc[16] = {
        15.0f, 23.0f, 35.0f, 53.0f, 80.0f, 120.5f, 181.25f, 272.375f,
        409.0625f, 614.09375f, 921.640625f, 1382.9609375f,
        2074.94140625f, 3112.912109375f, 4669.8681640625f, 7005.30224609375f};
    const uint32_t kre[16] = {16u, 24u, 36u, 54u, 81u, 122u, 183u, 274u,
                              411u, 616u, 923u, 1384u, 2076u, 3114u, 4671u, 7007u};
    sc = ksc[l]; re = kre[l]; dense = (l < 10) ? 1 : 0;
}

// Per-point cell setup: EXACT arithmetic of the reference (no FMA contraction).
__device__ __forceinline__ void setup_pt(float2 xy, float scale,
                                         uint32_t& gx, uint32_t& gy,
                                         float& fx, float& fy) {
    const float px  = __fadd_rn(__fmul_rn(xy.x, scale), 0.5f);
    const float py  = __fadd_rn(__fmul_rn(xy.y, scale), 0.5f);
    const float fpx = floorf(px);
    const float fpy = floorf(py);
    fx = px - fpx;
    fy = py - fpy;
    gx = (uint32_t)fpx;
    gy = (uint32_t)fpy;
}

// Accumulate in the reference's exact order: (0,0),(0,1),(1,0),(1,1).
// A = pair at dy=0 (lo: dx=0, hi: dx=1), B = pair at dy=1.
__device__ __forceinline__ float2 acc_pairs(PairLd A, PairLd B, float fx, float fy) {
    const float w00 = (1.0f - fx) * (1.0f - fy);
    const float w01 = (1.0f - fx) * fy;
    const float w10 = fx * (1.0f - fy);
    const float w11 = fx * fy;
    float ax = fmaf(A.lo.x, w00, 0.0f);
    float ay = fmaf(A.lo.y, w00, 0.0f);
    ax = fmaf(B.lo.x, w01, ax); ay = fmaf(B.lo.y, w01, ay);
    ax = fmaf(A.hi.x, w10, ax); ay = fmaf(A.hi.y, w10, ay);
    ax = fmaf(B.hi.x, w11, ax); ay = fmaf(B.hi.y, w11, ay);
    return make_float2(ax, ay);
}

__device__ __forceinline__ float2 acc_quad(float2 v00, float2 v01, float2 v10, float2 v11,
                                           float fx, float fy) {
    const float w00 = (1.0f - fx) * (1.0f - fy);
    const float w01 = (1.0f - fx) * fy;
    const float w10 = fx * (1.0f - fy);
    const float w11 = fx * fy;
    float ax = fmaf(v00.x, w00, 0.0f);
    float ay = fmaf(v00.y, w00, 0.0f);
    ax = fmaf(v01.x, w01, ax); ay = fmaf(v01.y, w01, ay);
    ax = fmaf(v10.x, w10, ax); ay = fmaf(v10.y, w10, ay);
    ax = fmaf(v11.x, w11, ax); ay = fmaf(v11.y, w11, ay);
    return make_float2(ax, ay);
}

// ---- hash8: levels 8..15, one level per XCD (blockIdx%8), 4 pts/thread. ----
__global__ __launch_bounds__(256) void hash8_kernel(
    const float* __restrict__ x,
    const float* __restrict__ table,
    float2* __restrict__ ws)
{
    const uint32_t slot  = blockIdx.x & 7u;   // -> XCD slot (round-robin dispatch)
    const uint32_t chunk = blockIdx.x >> 3;   // 0..2047
    const int      l     = 8 + (int)slot;
    float sc; uint32_t re; int de;
    level_consts(l, sc, re, de);
    const float2* __restrict__ tab =
        reinterpret_cast<const float2*>(table) + ((size_t)l << 19);
    float2* __restrict__ wsl = ws + (size_t)slot * kNPoints;

    const uint32_t base = chunk * 1024u + threadIdx.x;
    const float2* __restrict__ xv = reinterpret_cast<const float2*>(x);

    float2 xy[4];
#pragma unroll
    for (int k = 0; k < 4; ++k)   // NT: don't let the x stream evict the table
        xy[k] = nt_load_f2(xv + base + (uint32_t)k * 256u);

    uint32_t gx[4], gy[4];
    float    fx[4], fy[4];
#pragma unroll
    for (int k = 0; k < 4; ++k)
        setup_pt(xy[k], sc, gx[k], gy[k], fx[k], fy[k]);

    float2 r[4];
    if (de) {                      // levels 8,9: dense, corner-paired 16B loads
        PairLd A[4], B[4];
#pragma unroll
        for (int k = 0; k < 4; ++k) {      // issue all 8 loads back-to-back
            const uint32_t i00 = gx[k] + gy[k] * re;   // no wrap: res*(res+1) < T
            A[k] = load_pair(tab + i00);
            B[k] = load_pair(tab + i00 + re);
        }
#pragma unroll
        for (int k = 0; k < 4; ++k)
            r[k] = acc_pairs(A[k], B[k], fx[k], fy[k]);
    } else {                       // levels 10..15: spatial hash, 16 loads in flight
        float2 v[4][4];
#pragma unroll
        for (int k = 0; k < 4; ++k) {      // issue all 16 loads back-to-back
            const uint32_t cx = gx[k];
            const uint32_t K0 = gy[k] * kPrimeY;
            const uint32_t K1 = K0 + kPrimeY;
            v[k][0] = tab[(cx ^ K0) & kTMask];
            v[k][1] = tab[(cx ^ K1) & kTMask];
            v[k][2] = tab[((cx + 1u) ^ K0) & kTMask];
            v[k][3] = tab[((cx + 1u) ^ K1) & kTMask];
        }
#pragma unroll
        for (int k = 0; k < 4; ++k)
            r[k] = acc_quad(v[k][0], v[k][1], v[k][2], v[k][3], fx[k], fy[k]);
    }

#pragma unroll
    for (int k = 0; k < 4; ++k)   // NT: ws write stream bypasses the table's L2
        nt_store_f2(wsl + base + (uint32_t)k * 256u, r[k]);
}

// ---- merge: R3 skeleton (single-phase 36 KB LDS, measured 201 us) +
//      batched paired loads for the 8 dense levels. ----
__global__ __launch_bounds__(256) void merge_kernel(
    const float* __restrict__ x,
    const float* __restrict__ table,
    const float2* __restrict__ ws,    // [8][N]
    float* __restrict__ out)
{
    __shared__ float s[256 * 36];     // 36 KB rows of 36 floats: 16B-aligned
    const uint32_t tid = threadIdx.x;
    const uint32_t n   = blockIdx.x * 256u + tid;
    const float2   xy  = reinterpret_cast<const float2*>(x)[n];

    float fx[8], fy[8];
    PairLd A[8], B[8];
#pragma unroll
    for (int l = 0; l < 8; ++l) {     // issue all 16 table loads back-to-back
        float sc; uint32_t re; int de;
        level_consts(l, sc, re, de);
        const float2* tab = reinterpret_cast<const float2*>(table) + ((size_t)l << 19);
        uint32_t gx, gy;
        setup_pt(xy, sc, gx, gy, fx[l], fy[l]);
        const uint32_t i00 = gx + gy * re;             // dense: no wrap
        A[l] = load_pair(tab + i00);
        B[l] = load_pair(tab + i00 + re);
    }
    float2 wv[8];
#pragma unroll
    for (int j = 0; j < 8; ++j)       // 8 coalesced ws loads, also in flight
        wv[j] = ws[(size_t)j * kNPoints + n];

    float2* srow = reinterpret_cast<float2*>(&s[tid * 36]);
#pragma unroll
    for (int l = 0; l < 8; ++l)
        srow[l] = acc_pairs(A[l], B[l], fx[l], fy[l]);
#pragma unroll
    for (int j = 0; j < 8; ++j)
        srow[8 + j] = wv[j];
    __syncthreads();

    float4* outb = reinterpret_cast<float4*>(out + (size_t)blockIdx.x * 8192);
#pragma unroll
    for (int k = 0; k < 8; ++k) {
        const uint32_t q   = tid + (uint32_t)k * 256u;  // float4 index in block tile
        const uint32_t row = q >> 3;                    // point within block
        const uint32_t c   = (q & 7u) * 4u;             // column (floats)
        const float* sp = &s[row * 36 + c];
        outb[q] = make_float4(sp[0], sp[1], sp[2], sp[3]);  // coalesced
    }
}

// ---- Fallback: R1 single kernel (passed at 688 us) if ws is too small. ----
__global__ __launch_bounds__(256) void hashgrid_fwd_fallback(
    const float* __restrict__ x,
    const float* __restrict__ table,
    float* __restrict__ out)
{
    const uint32_t tid = blockIdx.x * blockDim.x + threadIdx.x;
    const uint32_t l   = tid & 15u;
    const uint32_t n   = tid >> 4;
    float sc; uint32_t re; int de;
    level_consts((int)l, sc, re, de);
    const float2 xy = reinterpret_cast<const float2*>(x)[n];
    const float2* tab = reinterpret_cast<const float2*>(table) + ((size_t)l << 19);
    uint32_t gx, gy; float fx, fy;
    setup_pt(xy, sc, gx, gy, fx, fy);
    float2 v00, v01, v10, v11;
    if (de) {
        const uint32_t i00 = gx + gy * re;
        v00 = tab[i00]; v10 = tab[i00 + 1u];
        v01 = tab[i00 + re]; v11 = tab[i00 + re + 1u];
    } else {
        const uint32_t K0 = gy * kPrimeY, K1 = K0 + kPrimeY;
        v00 = tab[(gx ^ K0) & kTMask];
        v01 = tab[(gx ^ K1) & kTMask];
        v10 = tab[((gx + 1u) ^ K0) & kTMask];
        v11 = tab[((gx + 1u) ^ K1) & kTMask];
    }
    const float2 r = acc_quad(v00, v01, v10, v11, fx, fy);
    reinterpret_cast<float2*>(out)[tid] = r;
}

extern "C" void kernel_launch(void* const* d_in, const int* in_sizes, int n_in,
                              void* d_out, int out_size, void* d_ws, size_t ws_size,
                              hipStream_t stream) {
    const float* x     = (const float*)d_in[0];
    const float* table = (const float*)d_in[1];
    float*       out   = (float*)d_out;

    const size_t need8 = (size_t)8 * kNPoints * sizeof(float2);  // 128 MB

    if (ws_size >= need8) {
        float2* ws = (float2*)d_ws;
        hash8_kernel<<<16384, 256, 0, stream>>>(x, table, ws);
        merge_kernel<<<kNPoints / 256, 256, 0, stream>>>(x, table, ws, out);
    } else {
        hashgrid_fwd_fallback<<<(kNPoints * 16) / 256, 256, 0, stream>>>(x, table, out);
    }
}